// Round 7
// baseline (300.439 us; speedup 1.0000x reference)
//
#include <hip/hip_runtime.h>
#include <math.h>

#define N_NODES 50000
#define N_EDGES 800000
#define N_CAND  100000
#define D       128
#define BN_EPS  1e-5f
#define SLOPE   0.01f

// bucketed counting sort for CSR
#define BSHIFT  7
#define NBKT    391      // ceil(50000 / 128)
#define SUBCAP  448      // per (bucket, blockIdx&7) capacity: mean 256, +12 sigma

typedef __attribute__((ext_vector_type(8))) short bf16x8;
typedef __attribute__((ext_vector_type(4))) float f32x4;

__device__ __forceinline__ float lrelu(float x){ return x >= 0.f ? x : SLOPE * x; }

__device__ __forceinline__ unsigned short f2bf_rn(float f){
  unsigned int u = __float_as_uint(f);
  unsigned int r = u + 0x7FFFu + ((u >> 16) & 1u);
  return (unsigned short)(r >> 16);
}
__device__ __forceinline__ float bf2f(unsigned short h){
  return __uint_as_float(((unsigned int)h) << 16);
}
__device__ __forceinline__ float4 bf4f(ushort4 u){
  return make_float4(__uint_as_float((unsigned)u.x << 16),
                     __uint_as_float((unsigned)u.y << 16),
                     __uint_as_float((unsigned)u.z << 16),
                     __uint_as_float((unsigned)u.w << 16));
}

// pack 2 f32 -> 2 bf16 in one inst ([15:0]=bf16(a), [31:16]=bf16(b))
__device__ __forceinline__ unsigned pk_bf16(float a, float b){
  unsigned r;
  asm("v_cvt_pk_bf16_f32 %0, %1, %2" : "=v"(r) : "v"(a), "v"(b));
  return r;
}
// split pair into hi + lo ( lo = rn(x - hi) -> self-correcting wrt cvt rounding )
__device__ __forceinline__ void split2(float a, float b, unsigned &h, unsigned &l){
  h = pk_bf16(a, b);
  float ra = a - __uint_as_float(h << 16);
  float rb = b - __uint_as_float(h & 0xffff0000u);
  l = pk_bf16(ra, rb);
}
// split a float4-pair (8 consecutive k) into A-fragment hi/lo
__device__ __forceinline__ void split8(const float4 &v0, const float4 &v1, uint4 &h, uint4 &l){
  split2(v0.x, v0.y, h.x, l.x);
  split2(v0.z, v0.w, h.y, l.y);
  split2(v1.x, v1.y, h.z, l.z);
  split2(v1.z, v1.w, h.w, l.w);
}

// ---------------- CSR build: bucketed counting sort ----------------
// Pass A: append edge to (dst>>7, blockIdx&7) sub-bucket. Sub-bucketing by
// block id keeps each append stream on (mostly) one XCD -> full-line
// write-back instead of the 17x partial-line amplification the old scattered
// k_fill showed (WRITE_SIZE 55MB for a 3.2MB array).
__global__ __launch_bounds__(256) void k_bucket(const int* __restrict__ src, const int* __restrict__ dst,
                                                int* __restrict__ bcnt, unsigned* __restrict__ ebkt, int E){
  int i = blockIdx.x * 256 + threadIdx.x;
  if (i < E){
    int d = dst[i];
    int cell = ((d >> BSHIFT) << 3) + (blockIdx.x & 7);
    int p = atomicAdd(&bcnt[cell], 1);
    ebkt[(size_t)cell * SUBCAP + p] = ((unsigned)(d & 127) << 16) | (unsigned)src[i];
  }
}

// Pass B: exclusive scan of bucket totals -> bbase; rowptr[N] = E.
__global__ __launch_bounds__(512) void k_bscan(const int* __restrict__ bcnt, int* __restrict__ bbase,
                                               int* __restrict__ rowptr){
  __shared__ int sd[512];
  int t = threadIdx.x;
  int tot = 0;
  if (t < NBKT){
    #pragma unroll
    for (int j = 0; j < 8; ++j) tot += bcnt[(t << 3) + j];
  }
  sd[t] = tot; __syncthreads();
  for (int off = 1; off < 512; off <<= 1){
    int v = (t >= off) ? sd[t - off] : 0;
    __syncthreads();
    sd[t] += v; __syncthreads();
  }
  if (t < NBKT) bbase[t] = sd[t] - tot;
  if (t == NBKT - 1) rowptr[N_NODES] = sd[t];
}

// Pass C: per-bucket local histogram + scan -> rowptr for the bucket's 128
// nodes, then place edges into eid16 within the bucket's CONTIGUOUS region
// (dense, single-block-owned -> no cross-XCD line sharing).
__global__ __launch_bounds__(256) void k_bfill(const int* __restrict__ bcnt, const int* __restrict__ bbase,
                                               const unsigned* __restrict__ ebkt,
                                               unsigned short* __restrict__ eid16,
                                               int* __restrict__ rowptr, int n){
  __shared__ int hist[128], lb[128], lcur[128];
  int t = threadIdx.x, b = blockIdx.x;
  if (t < 128) hist[t] = 0;
  __syncthreads();
  int base = bbase[b];
  #pragma unroll 1
  for (int j = 0; j < 8; ++j){
    int cj = bcnt[(b << 3) + j];
    const unsigned* eb = &ebkt[(size_t)((b << 3) + j) * SUBCAP];
    for (int idx = t; idx < cj; idx += 256) atomicAdd(&hist[eb[idx] >> 16], 1);
  }
  __syncthreads();
  if (t < 128) lb[t] = hist[t];
  __syncthreads();
  for (int off = 1; off < 128; off <<= 1){
    int v = (t < 128 && t >= off) ? lb[t - off] : 0;
    __syncthreads();
    if (t < 128) lb[t] += v;
    __syncthreads();
  }
  if (t < 128){
    int ex = lb[t] - hist[t];
    lcur[t] = ex;
    int node = (b << BSHIFT) + t;
    if (node < n) rowptr[node] = base + ex;
  }
  __syncthreads();
  #pragma unroll 1
  for (int j = 0; j < 8; ++j){
    int cj = bcnt[(b << 3) + j];
    const unsigned* eb = &ebkt[(size_t)((b << 3) + j) * SUBCAP];
    for (int idx = t; idx < cj; idx += 256){
      unsigned e = eb[idx];
      int p = atomicAdd(&lcur[e >> 16], 1);
      eid16[base + p] = (unsigned short)(e & 0xffffu);
    }
  }
}

// ---------------- weight transpose + bf16 hi/lo split (SAGE) ----------------
__global__ __launch_bounds__(256) void k_cvt_w(const float* __restrict__ ws, const float* __restrict__ wn,
                                               unsigned short* __restrict__ bth, unsigned short* __restrict__ btl){
  int col = blockIdx.x;       // 0..127
  int k   = threadIdx.x;      // 0..255
  float v = (k < 128) ? ws[k * D + col] : wn[(k - 128) * D + col];
  unsigned short hi = f2bf_rn(v);
  unsigned short lo = f2bf_rn(v - bf2f(hi));
  bth[col * 256 + k] = hi;
  btl[col * 256 + k] = lo;
}

// ---------------- MLP weight transpose + split: w[K x 64] -> T_h/T_l [64][Kpad] ----------------
__global__ __launch_bounds__(256) void k_cvt_mlp(const float* __restrict__ w, int K, int Kpad,
                                                 unsigned short* __restrict__ th, unsigned short* __restrict__ tl){
  int col = blockIdx.x;       // 0..63
  for (int k = threadIdx.x; k < Kpad; k += 256){
    float v = (k < K) ? w[k * 64 + col] : 0.f;
    unsigned short hi = f2bf_rn(v);
    th[col * Kpad + k] = hi;
    tl[col * Kpad + k] = f2bf_rn(v - bf2f(hi));
  }
}

// ---------------- x -> bf16 plane ----------------
__global__ __launch_bounds__(256) void k_cvt_x(const float* __restrict__ X, unsigned short* __restrict__ XB, int nel4){
  int i = blockIdx.x * 256 + threadIdx.x;
  if (i < nel4){
    float4 v = *reinterpret_cast<const float4*>(&X[(size_t)i * 4]);
    ushort4 u;
    u.x = f2bf_rn(v.x); u.y = f2bf_rn(v.y); u.z = f2bf_rn(v.z); u.w = f2bf_rn(v.w);
    *reinterpret_cast<ushort4*>(&XB[(size_t)i * 4]) = u;
  }
}

// ---------------- mean aggregation: bf16 gather, fp32 accumulate ----------------
__global__ __launch_bounds__(256) void k_agg_bf(const unsigned short* __restrict__ XB,
                                                const int* __restrict__ rowptr, const unsigned short* __restrict__ eid,
                                                float* __restrict__ AG, int n){
  int g = blockIdx.x * 8 + (threadIdx.x >> 5);   // node
  int l = threadIdx.x & 31;                      // 4-bf16 chunk
  if (g >= n) return;
  int e0 = rowptr[g], e1 = rowptr[g + 1];
  float4 a0 = make_float4(0.f,0.f,0.f,0.f);
  float4 a1 = make_float4(0.f,0.f,0.f,0.f);
  int e = e0;
  for (; e + 2 <= e1; e += 2){
    int s0 = eid[e], s1 = eid[e + 1];
    ushort4 u0 = *reinterpret_cast<const ushort4*>(&XB[(size_t)s0 * D + l * 4]);
    ushort4 u1 = *reinterpret_cast<const ushort4*>(&XB[(size_t)s1 * D + l * 4]);
    float4 f0 = bf4f(u0), f1 = bf4f(u1);
    a0.x += f0.x; a0.y += f0.y; a0.z += f0.z; a0.w += f0.w;
    a1.x += f1.x; a1.y += f1.y; a1.z += f1.z; a1.w += f1.w;
  }
  if (e < e1){
    int s0 = eid[e];
    ushort4 u0 = *reinterpret_cast<const ushort4*>(&XB[(size_t)s0 * D + l * 4]);
    float4 f0 = bf4f(u0);
    a0.x += f0.x; a0.y += f0.y; a0.z += f0.z; a0.w += f0.w;
  }
  float sc = 1.f / fmaxf((float)(e1 - e0), 1.f);
  float4 o;
  o.x = (a0.x + a1.x) * sc; o.y = (a0.y + a1.y) * sc;
  o.z = (a0.z + a1.z) * sc; o.w = (a0.w + a1.w) * sc;
  *reinterpret_cast<float4*>(&AG[(size_t)g * D + l * 4]) = o;
}

// ---------------- SAGE layer via split-bf16 MFMA ----------------
__global__ __launch_bounds__(256) void k_sage_mfma(const float* __restrict__ XS, const float* __restrict__ AG,
    const unsigned short* __restrict__ BTH, const unsigned short* __restrict__ BTL,
    const float* __restrict__ Bb, const float* __restrict__ GM, const float* __restrict__ BT,
    const float* __restrict__ RM, const float* __restrict__ RV,
    float* __restrict__ H, unsigned short* __restrict__ HB, int n, int donan)
{
  __shared__ unsigned short Ah[64 * 40];
  __shared__ unsigned short Al[64 * 40];
  __shared__ unsigned short Bh[128 * 40];
  __shared__ unsigned short Bl[128 * 40];

  int t  = threadIdx.x;
  int l  = t & 63;
  int wv = t >> 6;          // wave 0..3 -> rows wv*16..+15
  int lm = l & 15;          // frag row (A) / col (B,D)
  int lk = l >> 4;          // k-group 0..3
  int node0 = blockIdx.x * 64;

  f32x4 acc[8];
  #pragma unroll
  for (int f = 0; f < 8; ++f) acc[f] = (f32x4){0.f, 0.f, 0.f, 0.f};

  for (int step = 0; step < 8; ++step){
    int k0 = step * 32;                          // global k in [0,256)
    const float* srcA = (step < 4) ? XS : AG;
    int koff = (step < 4) ? k0 : (k0 - 128);

    __syncthreads();
    // ---- stage A: 64 rows x 32 k fp32 -> hi/lo bf16 ----
    #pragma unroll
    for (int i = 0; i < 2; ++i){
      int c   = t + i * 256;
      int row = c >> 3, c4 = c & 7;
      int node = min(node0 + row, n - 1);
      float4 v = *reinterpret_cast<const float4*>(&srcA[(size_t)node * D + koff + c4 * 4]);
      const float* vp = (const float*)&v;
      unsigned short hh[4], ll[4];
      #pragma unroll
      for (int j = 0; j < 4; ++j){
        unsigned short hi = f2bf_rn(vp[j]);
        hh[j] = hi;
        ll[j] = f2bf_rn(vp[j] - bf2f(hi));
      }
      uint2 wh, wl;
      wh.x = (unsigned)hh[0] | ((unsigned)hh[1] << 16);
      wh.y = (unsigned)hh[2] | ((unsigned)hh[3] << 16);
      wl.x = (unsigned)ll[0] | ((unsigned)ll[1] << 16);
      wl.y = (unsigned)ll[2] | ((unsigned)ll[3] << 16);
      *reinterpret_cast<uint2*>(&Ah[row * 40 + c4 * 4]) = wh;
      *reinterpret_cast<uint2*>(&Al[row * 40 + c4 * 4]) = wl;
    }
    // ---- stage B: 128 cols x 32 k bf16 hi+lo ----
    #pragma unroll
    for (int i = 0; i < 2; ++i){
      int c   = t + i * 256;
      int col = c >> 2, q = c & 3;
      *reinterpret_cast<uint4*>(&Bh[col * 40 + q * 8]) =
          *reinterpret_cast<const uint4*>(&BTH[col * 256 + k0 + q * 8]);
      *reinterpret_cast<uint4*>(&Bl[col * 40 + q * 8]) =
          *reinterpret_cast<const uint4*>(&BTL[col * 256 + k0 + q * 8]);
    }
    __syncthreads();

    // ---- MFMA: 8 col-frags x 3 split terms ----
    bf16x8 afh = *reinterpret_cast<const bf16x8*>(&Ah[(wv * 16 + lm) * 40 + lk * 8]);
    bf16x8 afl = *reinterpret_cast<const bf16x8*>(&Al[(wv * 16 + lm) * 40 + lk * 8]);
    #pragma unroll
    for (int f = 0; f < 8; ++f){
      bf16x8 bfh = *reinterpret_cast<const bf16x8*>(&Bh[(f * 16 + lm) * 40 + lk * 8]);
      bf16x8 bfl = *reinterpret_cast<const bf16x8*>(&Bl[(f * 16 + lm) * 40 + lk * 8]);
      acc[f] = __builtin_amdgcn_mfma_f32_16x16x32_bf16(afh, bfh, acc[f], 0, 0, 0);
      acc[f] = __builtin_amdgcn_mfma_f32_16x16x32_bf16(afl, bfh, acc[f], 0, 0, 0);
      acc[f] = __builtin_amdgcn_mfma_f32_16x16x32_bf16(afh, bfl, acc[f], 0, 0, 0);
    }
  }

  // ---- epilogue: BN + leaky relu (+ nan_to_num layer 2) ----
  #pragma unroll
  for (int f = 0; f < 8; ++f){
    int col = f * 16 + lm;
    float s  = GM[col] * rsqrtf(RV[col] + BN_EPS);
    float cj = (Bb[col] - RM[col]) * s + BT[col];
    #pragma unroll
    for (int r = 0; r < 4; ++r){
      int node = node0 + wv * 16 + lk * 4 + r;
      if (node < n){
        float v = lrelu(acc[f][r] * s + cj);
        if (donan && (v != v)) v = 1e-14f;
        H[(size_t)node * D + col] = v;
        if (HB) HB[(size_t)node * D + col] = f2bf_rn(v);
      }
    }
  }
}

// ---------------- candidate MLP via split-bf16 MFMA ----------------
__global__ __launch_bounds__(256) void k_mlp_mfma(const float* __restrict__ H,
    const int* __restrict__ cu, const int* __restrict__ cv, const float* __restrict__ cf,
    const unsigned short* __restrict__ W0H, const unsigned short* __restrict__ W0L,
    const float* __restrict__ mw0, const float* __restrict__ mb0,
    const unsigned short* __restrict__ W1H, const unsigned short* __restrict__ W1L,
    const float* __restrict__ mb1, const float* __restrict__ mw2, const float* __restrict__ mb2,
    float* __restrict__ y, int C)
{
  __shared__ unsigned short zh[4][32 * 72];   // per-wave z tile, hi (rows 144B)
  __shared__ unsigned short zl[4][32 * 72];   // per-wave z tile, lo

  int t = threadIdx.x;
  int wv = t >> 6, l = t & 63, lm = l & 15, lk = l >> 4;
  int candbase = blockIdx.x * 128 + wv * 32;

  int c0 = min(candbase + lm,      C - 1);
  int c1 = min(candbase + 16 + lm, C - 1);
  int nu0 = cu[c0], nv0 = cv[c0];
  int nu1 = cu[c1], nv1 = cv[c1];

  // ---- layer 1: K = 256 via MFMA ----
  f32x4 acc[2][4];
  #pragma unroll
  for (int m = 0; m < 2; ++m)
    #pragma unroll
    for (int f = 0; f < 4; ++f) acc[m][f] = (f32x4){0.f, 0.f, 0.f, 0.f};

  #pragma unroll
  for (int s = 0; s < 8; ++s){
    int n0 = (s < 4) ? nu0 : nv0;
    int n1 = (s < 4) ? nu1 : nv1;
    int koff = (s & 3) * 32 + lk * 8;
    const float4* p0 = reinterpret_cast<const float4*>(&H[(size_t)n0 * D + koff]);
    const float4* p1 = reinterpret_cast<const float4*>(&H[(size_t)n1 * D + koff]);
    float4 a00 = p0[0], a01 = p0[1];
    float4 a10 = p1[0], a11 = p1[1];
    uint4 h0, l0, h1, l1;
    split8(a00, a01, h0, l0);
    split8(a10, a11, h1, l1);
    bf16x8 afh0 = *reinterpret_cast<bf16x8*>(&h0);
    bf16x8 afl0 = *reinterpret_cast<bf16x8*>(&l0);
    bf16x8 afh1 = *reinterpret_cast<bf16x8*>(&h1);
    bf16x8 afl1 = *reinterpret_cast<bf16x8*>(&l1);

    int k0 = s * 32 + lk * 8;
    #pragma unroll
    for (int f = 0; f < 4; ++f){
      int col = f * 16 + lm;
      bf16x8 bh = *reinterpret_cast<const bf16x8*>(&W0H[(size_t)col * 264 + k0]);
      bf16x8 bl = *reinterpret_cast<const bf16x8*>(&W0L[(size_t)col * 264 + k0]);
      acc[0][f] = __builtin_amdgcn_mfma_f32_16x16x32_bf16(afh0, bh, acc[0][f], 0, 0, 0);
      acc[0][f] = __builtin_amdgcn_mfma_f32_16x16x32_bf16(afl0, bh, acc[0][f], 0, 0, 0);
      acc[0][f] = __builtin_amdgcn_mfma_f32_16x16x32_bf16(afh0, bl, acc[0][f], 0, 0, 0);
      acc[1][f] = __builtin_amdgcn_mfma_f32_16x16x32_bf16(afh1, bh, acc[1][f], 0, 0, 0);
      acc[1][f] = __builtin_amdgcn_mfma_f32_16x16x32_bf16(afl1, bh, acc[1][f], 0, 0, 0);
      acc[1][f] = __builtin_amdgcn_mfma_f32_16x16x32_bf16(afh1, bl, acc[1][f], 0, 0, 0);
    }
  }

  // ---- L1 epilogue: bias + feat term + lrelu, write z hi/lo to LDS ----
  float cfv[2][4];
  #pragma unroll
  for (int m = 0; m < 2; ++m)
    #pragma unroll
    for (int r = 0; r < 4; ++r)
      cfv[m][r] = cf[min(candbase + m * 16 + lk * 4 + r, C - 1)];

  #pragma unroll
  for (int f = 0; f < 4; ++f){
    int col = f * 16 + lm;
    float b0v = mb0[col];
    float wfv = mw0[256 * 64 + col];
    #pragma unroll
    for (int m = 0; m < 2; ++m){
      #pragma unroll
      for (int r = 0; r < 4; ++r){
        int cl = m * 16 + lk * 4 + r;
        float z = lrelu(acc[m][f][r] + b0v + cfv[m][r] * wfv);
        unsigned short h16 = f2bf_rn(z);
        zh[wv][cl * 72 + col] = h16;
        zl[wv][cl * 72 + col] = f2bf_rn(z - bf2f(h16));
      }
    }
  }
  // wave-local LDS: hardware lgkmcnt ordering covers write->read, no barrier

  // ---- layer 2: K = 64 via MFMA ----
  f32x4 a2[2][4];
  #pragma unroll
  for (int m = 0; m < 2; ++m)
    #pragma unroll
    for (int f = 0; f < 4; ++f) a2[m][f] = (f32x4){0.f, 0.f, 0.f, 0.f};

  #pragma unroll
  for (int s2 = 0; s2 < 2; ++s2){
    int kk = s2 * 32 + lk * 8;
    bf16x8 azh0 = *reinterpret_cast<const bf16x8*>(&zh[wv][(0 * 16 + lm) * 72 + kk]);
    bf16x8 azl0 = *reinterpret_cast<const bf16x8*>(&zl[wv][(0 * 16 + lm) * 72 + kk]);
    bf16x8 azh1 = *reinterpret_cast<const bf16x8*>(&zh[wv][(1 * 16 + lm) * 72 + kk]);
    bf16x8 azl1 = *reinterpret_cast<const bf16x8*>(&zl[wv][(1 * 16 + lm) * 72 + kk]);
    #pragma unroll
    for (int f = 0; f < 4; ++f){
      int col = f * 16 + lm;
      bf16x8 bh = *reinterpret_cast<const bf16x8*>(&W1H[(size_t)col * 64 + kk]);
      bf16x8 bl = *reinterpret_cast<const bf16x8*>(&W1L[(size_t)col * 64 + kk]);
      a2[0][f] = __builtin_amdgcn_mfma_f32_16x16x32_bf16(azh0, bh, a2[0][f], 0, 0, 0);
      a2[0][f] = __builtin_amdgcn_mfma_f32_16x16x32_bf16(azl0, bh, a2[0][f], 0, 0, 0);
      a2[0][f] = __builtin_amdgcn_mfma_f32_16x16x32_bf16(azh0, bl, a2[0][f], 0, 0, 0);
      a2[1][f] = __builtin_amdgcn_mfma_f32_16x16x32_bf16(azh1, bh, a2[1][f], 0, 0, 0);
      a2[1][f] = __builtin_amdgcn_mfma_f32_16x16x32_bf16(azl1, bh, a2[1][f], 0, 0, 0);
      a2[1][f] = __builtin_amdgcn_mfma_f32_16x16x32_bf16(azh1, bl, a2[1][f], 0, 0, 0);
    }
  }

  // ---- layer 3: 64 -> 1 : per-lane partial + 16-lane xor reduce ----
  float p00 = 0.f, p01 = 0.f, p02 = 0.f, p03 = 0.f;
  float p10 = 0.f, p11 = 0.f, p12 = 0.f, p13 = 0.f;
  #pragma unroll
  for (int f = 0; f < 4; ++f){
    int col = f * 16 + lm;
    float b1v = mb1[col];
    float w2v = mw2[col];
    p00 = fmaf(lrelu(a2[0][f][0] + b1v), w2v, p00);
    p01 = fmaf(lrelu(a2[0][f][1] + b1v), w2v, p01);
    p02 = fmaf(lrelu(a2[0][f][2] + b1v), w2v, p02);
    p03 = fmaf(lrelu(a2[0][f][3] + b1v), w2v, p03);
    p10 = fmaf(lrelu(a2[1][f][0] + b1v), w2v, p10);
    p11 = fmaf(lrelu(a2[1][f][1] + b1v), w2v, p11);
    p12 = fmaf(lrelu(a2[1][f][2] + b1v), w2v, p12);
    p13 = fmaf(lrelu(a2[1][f][3] + b1v), w2v, p13);
  }
  #pragma unroll
  for (int off = 1; off < 16; off <<= 1){
    p00 += __shfl_xor(p00, off); p01 += __shfl_xor(p01, off);
    p02 += __shfl_xor(p02, off); p03 += __shfl_xor(p03, off);
    p10 += __shfl_xor(p10, off); p11 += __shfl_xor(p11, off);
    p12 += __shfl_xor(p12, off); p13 += __shfl_xor(p13, off);
  }
  if (lm == 0){
    float b2 = mb2[0];
    int base0 = candbase + lk * 4;
    int base1 = candbase + 16 + lk * 4;
    if (base0 + 0 < C) y[base0 + 0] = p00 + b2;
    if (base0 + 1 < C) y[base0 + 1] = p01 + b2;
    if (base0 + 2 < C) y[base0 + 2] = p02 + b2;
    if (base0 + 3 < C) y[base0 + 3] = p03 + b2;
    if (base1 + 0 < C) y[base1 + 0] = p10 + b2;
    if (base1 + 1 < C) y[base1 + 1] = p11 + b2;
    if (base1 + 2 < C) y[base1 + 2] = p12 + b2;
    if (base1 + 3 < C) y[base1 + 3] = p13 + b2;
  }
}

// ---------------- softmax over C logits ----------------
__global__ __launch_bounds__(256) void k_red1(const float* __restrict__ y,
                                              float* __restrict__ bmax, float* __restrict__ bsum, int C){
  __shared__ float sm[4];
  __shared__ float ss[4];
  int t = threadIdx.x;
  float m = -3.4e38f;
  for (int i = blockIdx.x * 256 + t; i < C; i += gridDim.x * 256) m = fmaxf(m, y[i]);
  for (int o = 32; o; o >>= 1) m = fmaxf(m, __shfl_xor(m, o));
  if ((t & 63) == 0) sm[t >> 6] = m;
  __syncthreads();
  float bm = fmaxf(fmaxf(sm[0], sm[1]), fmaxf(sm[2], sm[3]));
  float s = 0.f;
  for (int i = blockIdx.x * 256 + t; i < C; i += gridDim.x * 256) s += expf(y[i] - bm);
  for (int o = 32; o; o >>= 1) s += __shfl_xor(s, o);
  if ((t & 63) == 0) ss[t >> 6] = s;
  __syncthreads();
  if (t == 0){ bmax[blockIdx.x] = bm; bsum[blockIdx.x] = ss[0] + ss[1] + ss[2] + ss[3]; }
}

__global__ __launch_bounds__(256) void k_red2(const float* __restrict__ bmax, const float* __restrict__ bsum,
                                              float* __restrict__ g, int nb){
  __shared__ float sm[4];
  __shared__ float ss[4];
  int t = threadIdx.x;
  float m0 = (t < nb) ? bmax[t] : -3.4e38f;
  float m = m0;
  for (int o = 32; o; o >>= 1) m = fmaxf(m, __shfl_xor(m, o));
  if ((t & 63) == 0) sm[t >> 6] = m;
  __syncthreads();
  float gm = fmaxf(fmaxf(sm[0], sm[1]), fmaxf(sm[2], sm[3]));
  float s = (t < nb) ? bsum[t] * expf(m0 - gm) : 0.f;
  for (int o = 32; o; o >>= 1) s += __shfl_xor(s, o);
  if ((t & 63) == 0) ss[t >> 6] = s;
  __syncthreads();
  if (t == 0){ g[0] = gm; g[1] = 1.f / (ss[0] + ss[1] + ss[2] + ss[3]); }
}

__global__ __launch_bounds__(256) void k_red3(const float* __restrict__ y, const float* __restrict__ g,
                                              float* __restrict__ out, int C){
  int i = blockIdx.x * 256 + threadIdx.x;
  if (i < C) out[i] = expf(y[i] - g[0]) * g[1];
}

extern "C" void kernel_launch(void* const* d_in, const int* in_sizes, int n_in,
                              void* d_out, int out_size, void* d_ws, size_t ws_size,
                              hipStream_t stream)
{
  const float* x   = (const float*)d_in[0];
  const int*   src = (const int*)  d_in[1];
  const int*   dst = (const int*)  d_in[2];
  const int*   cu  = (const int*)  d_in[3];
  const int*   cv  = (const int*)  d_in[4];
  const float* cf  = (const float*)d_in[5];
  const float* ws0 = (const float*)d_in[6];
  const float* wn0 = (const float*)d_in[7];
  const float* b0  = (const float*)d_in[8];
  const float* g0  = (const float*)d_in[9];
  const float* be0 = (const float*)d_in[10];
  const float* rm0 = (const float*)d_in[11];
  const float* rv0 = (const float*)d_in[12];
  const float* ws1 = (const float*)d_in[13];
  const float* wn1 = (const float*)d_in[14];
  const float* b1  = (const float*)d_in[15];
  const float* g1  = (const float*)d_in[16];
  const float* be1 = (const float*)d_in[17];
  const float* rm1 = (const float*)d_in[18];
  const float* rv1 = (const float*)d_in[19];
  const float* mw0 = (const float*)d_in[20];
  const float* mb0 = (const float*)d_in[21];
  const float* mw1 = (const float*)d_in[22];
  const float* mb1 = (const float*)d_in[23];
  const float* mw2 = (const float*)d_in[24];
  const float* mb2 = (const float*)d_in[25];

  float* out = (float*)d_out;   // [C] y then [C] softmax

  char* w = (char*)d_ws;
  float* aggn  = (float*)w; w += (size_t)N_NODES * D * 4;
  float* h0    = (float*)w; w += (size_t)N_NODES * D * 4;
  float* h1    = (float*)w; w += (size_t)N_NODES * D * 4;
  int* cnt     = (int*)w;   w += (size_t)N_NODES * 4;          // -> SAGE weights L0
  int* rowptr  = (int*)w;   w += (size_t)(N_NODES + 1) * 4;
  int* cur     = (int*)w;   w += (size_t)N_NODES * 4;          // -> SAGE weights L1
  int* eid     = (int*)w;   w += (size_t)N_EDGES * 4;          // holds eid16 (ushort)
  int* bcnt    = (int*)w;   w += (size_t)(NBKT * 8) * 4;
  int* bbase   = (int*)w;   w += (size_t)(NBKT + 1) * 4;
  float* bmax  = (float*)w; w += 256 * 4;
  float* bsumF = (float*)w; w += 256 * 4;
  float* gred  = (float*)w; w += 2 * 4;
  // split MLP weights (transposed): w0 [64][264] hi/lo, w1 [64][64] hi/lo
  unsigned short* w0th = (unsigned short*)w; w += (size_t)64 * 264 * 2;
  unsigned short* w0tl = (unsigned short*)w; w += (size_t)64 * 264 * 2;
  unsigned short* w1th = (unsigned short*)w; w += (size_t)64 * 64 * 2;
  unsigned short* w1tl = (unsigned short*)w; w += (size_t)64 * 64 * 2;

  unsigned short* eid16 = (unsigned short*)eid;

  // edge buckets OVERLAY h0 (h0 only live sage0 -> sage1, after CSR build):
  unsigned* ebkt = (unsigned*)h0;      // NBKT*8*SUBCAP*4 = 5.6 MB << 25.6 MB

  // bf16 gather planes OVERLAY the h1 region:
  //   xb  live [cvt_x .. agg0],  hb0 live [sage0 .. agg1],  h1 live [sage1 .. mlp]
  unsigned short* xb  = (unsigned short*)h1;
  unsigned short* hb0 = xb + (size_t)N_NODES * D;

  // split-bf16 SAGE weight buffers alias the cnt/cur scratch (never used as
  // counters anymore):
  unsigned short* bth0 = (unsigned short*)cnt;
  unsigned short* btl0 = bth0 + 128 * 256;
  unsigned short* bth1 = (unsigned short*)cur;
  unsigned short* btl1 = bth1 + 128 * 256;

  // ---- CSR build (bucketed counting sort; all writes dense) ----
  hipMemsetAsync(bcnt, 0, (size_t)(NBKT * 8) * 4, stream);
  k_bucket<<<(N_EDGES + 255) / 256, 256, 0, stream>>>(src, dst, bcnt, ebkt, N_EDGES);
  k_bscan <<<1, 512, 0, stream>>>(bcnt, bbase, rowptr);
  k_bfill <<<NBKT, 256, 0, stream>>>(bcnt, bbase, ebkt, eid16, rowptr, N_NODES);

  // ---- weight conversions (independent) ----
  k_cvt_w<<<128, 256, 0, stream>>>(ws0, wn0, bth0, btl0);
  k_cvt_w<<<128, 256, 0, stream>>>(ws1, wn1, bth1, btl1);
  k_cvt_mlp<<<64, 256, 0, stream>>>(mw0, 257, 264, w0th, w0tl);
  k_cvt_mlp<<<64, 256, 0, stream>>>(mw1, 64, 64, w1th, w1tl);
  k_cvt_x<<<(N_NODES * D / 4 + 255) / 256, 256, 0, stream>>>(x, xb, N_NODES * D / 4);

  int GB = (N_NODES + 63) / 64;     // 782
  k_agg_bf<<<(N_NODES + 7) / 8, 256, 0, stream>>>(xb, rowptr, eid16, aggn, N_NODES);
  k_sage_mfma<<<GB, 256, 0, stream>>>(x,  aggn, bth0, btl0, b0, g0, be0, rm0, rv0, h0, hb0, N_NODES, 0);
  k_agg_bf<<<(N_NODES + 7) / 8, 256, 0, stream>>>(hb0, rowptr, eid16, aggn, N_NODES);
  k_sage_mfma<<<GB, 256, 0, stream>>>(h0, aggn, bth1, btl1, b1, g1, be1, rm1, rv1, h1, (unsigned short*)0, N_NODES, 1);

  k_mlp_mfma<<<(N_CAND + 127) / 128, 256, 0, stream>>>(h1, cu, cv, cf,
      w0th, w0tl, mw0, mb0, w1th, w1tl, mb1, mw2, mb2, out, N_CAND);

  k_red1<<<256, 256, 0, stream>>>(out, bmax, bsumF, N_CAND);
  k_red2<<<1, 256, 0, stream>>>(bmax, bsumF, gred, 256);
  k_red3<<<(N_CAND + 255) / 256, 256, 0, stream>>>(out, gred, out + N_CAND, N_CAND);
}

// Round 8
// 235.444 us; speedup vs baseline: 1.2761x; 1.2761x over previous
//
#include <hip/hip_runtime.h>
#include <math.h>

#define N_NODES 50000
#define N_EDGES 800000
#define N_CAND  100000
#define D       128
#define BN_EPS  1e-5f
#define SLOPE   0.01f

// tiled-binning CSR build
#define NB2     196      // coarse buckets of 256 nodes (d >> 8), covers 50176
#define TILE    4096     // edges per k_bin block
#define NTILE   196      // 196 * 4096 = 802816 >= E
#define BCAP    4736     // per-bucket capacity: mean 4096, +10 sigma

typedef __attribute__((ext_vector_type(8))) short bf16x8;
typedef __attribute__((ext_vector_type(4))) float f32x4;

__device__ __forceinline__ float lrelu(float x){ return x >= 0.f ? x : SLOPE * x; }

__device__ __forceinline__ unsigned short f2bf_rn(float f){
  unsigned int u = __float_as_uint(f);
  unsigned int r = u + 0x7FFFu + ((u >> 16) & 1u);
  return (unsigned short)(r >> 16);
}
__device__ __forceinline__ float bf2f(unsigned short h){
  return __uint_as_float(((unsigned int)h) << 16);
}
__device__ __forceinline__ float4 bf4f(ushort4 u){
  return make_float4(__uint_as_float((unsigned)u.x << 16),
                     __uint_as_float((unsigned)u.y << 16),
                     __uint_as_float((unsigned)u.z << 16),
                     __uint_as_float((unsigned)u.w << 16));
}

// pack 2 f32 -> 2 bf16 in one inst ([15:0]=bf16(a), [31:16]=bf16(b))
__device__ __forceinline__ unsigned pk_bf16(float a, float b){
  unsigned r;
  asm("v_cvt_pk_bf16_f32 %0, %1, %2" : "=v"(r) : "v"(a), "v"(b));
  return r;
}
// split pair into hi + lo ( lo = rn(x - hi) -> self-correcting wrt cvt rounding )
__device__ __forceinline__ void split2(float a, float b, unsigned &h, unsigned &l){
  h = pk_bf16(a, b);
  float ra = a - __uint_as_float(h << 16);
  float rb = b - __uint_as_float(h & 0xffff0000u);
  l = pk_bf16(ra, rb);
}
// split a float4-pair (8 consecutive k) into A-fragment hi/lo
__device__ __forceinline__ void split8(const float4 &v0, const float4 &v1, uint4 &h, uint4 &l){
  split2(v0.x, v0.y, h.x, l.x);
  split2(v0.z, v0.w, h.y, l.y);
  split2(v1.x, v1.y, h.z, l.z);
  split2(v1.z, v1.w, h.w, l.w);
}

// ---------------- CSR build: LDS-staged tiled binning ----------------
// Pass A: each block bins a 4096-edge tile into 196 coarse buckets (d>>8)
// entirely in LDS, reserves one contiguous global range per (tile,bucket)
// with a single atomicAdd, then burst-writes bucket-ordered runs (~84B each)
// -> coalesced-by-construction, no per-edge scattered stores (the round-7
// k_bucket showed 9x write amplification + 256-deep same-address atomic
// serialization; this has ~1.5x and 196-deep).
__global__ __launch_bounds__(256) void k_bin(const int* __restrict__ src, const int* __restrict__ dst,
                                             int* __restrict__ gcnt, unsigned* __restrict__ ebin, int E){
  __shared__ unsigned stage[TILE];
  __shared__ int hist[256], lscan[256], lex[256], lcur[256], gbase[256];
  __shared__ int stot;
  int t = threadIdx.x;
  int e0 = blockIdx.x * TILE;

  hist[t] = 0;
  __syncthreads();

  unsigned pk[16]; int bk[16]; bool ok[16];
  #pragma unroll
  for (int j = 0; j < 16; ++j){
    int i = e0 + j * 256 + t;
    ok[j] = (i < E);
    if (ok[j]){
      int d = dst[i];
      pk[j] = ((unsigned)d << 16) | (unsigned)src[i];
      bk[j] = d >> 8;
      atomicAdd(&hist[bk[j]], 1);
    }
  }
  __syncthreads();

  // inclusive scan of hist -> lscan
  lscan[t] = hist[t];
  __syncthreads();
  for (int off = 1; off < 256; off <<= 1){
    int v = (t >= off) ? lscan[t - off] : 0;
    __syncthreads();
    lscan[t] += v;
    __syncthreads();
  }
  int ex = lscan[t] - hist[t];
  lex[t]  = ex;
  lcur[t] = ex;
  if (t < NB2) gbase[t] = hist[t] ? atomicAdd(&gcnt[t], hist[t]) : 0;
  if (t == 255) stot = lscan[255];
  __syncthreads();

  // scatter tile into LDS, ordered by bucket
  #pragma unroll
  for (int j = 0; j < 16; ++j){
    if (ok[j]){
      int p = atomicAdd(&lcur[bk[j]], 1);
      stage[p] = pk[j];
    }
  }
  __syncthreads();

  // burst write: runs are contiguous in both LDS and global
  int tot = stot;
  for (int i = t; i < tot; i += 256){
    unsigned e = stage[i];
    int b = (int)(e >> 24);                 // (d >> 8) = top 9 bits of d<<16 -> e>>24
    ebin[(size_t)b * BCAP + gbase[b] + (i - lex[b])] = e;
  }
}

// Pass B: exclusive scan of bucket totals -> bbase; rowptr[N] = E.
__global__ __launch_bounds__(256) void k_bscan2(const int* __restrict__ gcnt, int* __restrict__ bbase,
                                                int* __restrict__ rowptr){
  __shared__ int sd[256];
  int t = threadIdx.x;
  int v = (t < NB2) ? gcnt[t] : 0;
  sd[t] = v; __syncthreads();
  for (int off = 1; off < 256; off <<= 1){
    int a = (t >= off) ? sd[t - off] : 0;
    __syncthreads();
    sd[t] += a; __syncthreads();
  }
  if (t < NB2) bbase[t] = sd[t] - v;
  if (t == NB2 - 1) rowptr[N_NODES] = sd[t];
}

// Pass C: per-bucket counting sort over its 256 nodes -> rowptr + eid16.
// All reads/writes land in a dense single-block-owned region (L2-resident).
__global__ __launch_bounds__(256) void k_bfin(const int* __restrict__ gcnt, const int* __restrict__ bbase,
                                              const unsigned* __restrict__ ebin,
                                              unsigned short* __restrict__ eid16,
                                              int* __restrict__ rowptr, int n){
  __shared__ int hist[256], lb[256], lcur[256];
  int t = threadIdx.x, b = blockIdx.x;
  int cb   = gcnt[b];
  int base = bbase[b];
  const unsigned* eb = &ebin[(size_t)b * BCAP];
  hist[t] = 0;
  __syncthreads();
  for (int idx = t; idx < cb; idx += 256) atomicAdd(&hist[(eb[idx] >> 16) & 255], 1);
  __syncthreads();
  lb[t] = hist[t];
  __syncthreads();
  for (int off = 1; off < 256; off <<= 1){
    int v = (t >= off) ? lb[t - off] : 0;
    __syncthreads();
    lb[t] += v; __syncthreads();
  }
  int ex = lb[t] - hist[t];
  lcur[t] = ex;
  int node = (b << 8) + t;
  if (node < n) rowptr[node] = base + ex;
  __syncthreads();
  for (int idx = t; idx < cb; idx += 256){
    unsigned e = eb[idx];
    int p = atomicAdd(&lcur[(e >> 16) & 255], 1);
    eid16[base + p] = (unsigned short)(e & 0xffffu);
  }
}

// ---------------- weight transpose + bf16 hi/lo split (SAGE) ----------------
__global__ __launch_bounds__(256) void k_cvt_w(const float* __restrict__ ws, const float* __restrict__ wn,
                                               unsigned short* __restrict__ bth, unsigned short* __restrict__ btl){
  int col = blockIdx.x;       // 0..127
  int k   = threadIdx.x;      // 0..255
  float v = (k < 128) ? ws[k * D + col] : wn[(k - 128) * D + col];
  unsigned short hi = f2bf_rn(v);
  unsigned short lo = f2bf_rn(v - bf2f(hi));
  bth[col * 256 + k] = hi;
  btl[col * 256 + k] = lo;
}

// ---------------- MLP weight transpose + split: w[K x 64] -> T_h/T_l [64][Kpad] ----------------
__global__ __launch_bounds__(256) void k_cvt_mlp(const float* __restrict__ w, int K, int Kpad,
                                                 unsigned short* __restrict__ th, unsigned short* __restrict__ tl){
  int col = blockIdx.x;       // 0..63
  for (int k = threadIdx.x; k < Kpad; k += 256){
    float v = (k < K) ? w[k * 64 + col] : 0.f;
    unsigned short hi = f2bf_rn(v);
    th[col * Kpad + k] = hi;
    tl[col * Kpad + k] = f2bf_rn(v - bf2f(hi));
  }
}

// ---------------- x -> bf16 plane ----------------
__global__ __launch_bounds__(256) void k_cvt_x(const float* __restrict__ X, unsigned short* __restrict__ XB, int nel4){
  int i = blockIdx.x * 256 + threadIdx.x;
  if (i < nel4){
    float4 v = *reinterpret_cast<const float4*>(&X[(size_t)i * 4]);
    ushort4 u;
    u.x = f2bf_rn(v.x); u.y = f2bf_rn(v.y); u.z = f2bf_rn(v.z); u.w = f2bf_rn(v.w);
    *reinterpret_cast<ushort4*>(&XB[(size_t)i * 4]) = u;
  }
}

// ---------------- mean aggregation: bf16 gather, fp32 accumulate ----------------
__global__ __launch_bounds__(256) void k_agg_bf(const unsigned short* __restrict__ XB,
                                                const int* __restrict__ rowptr, const unsigned short* __restrict__ eid,
                                                float* __restrict__ AG, int n){
  int g = blockIdx.x * 8 + (threadIdx.x >> 5);   // node
  int l = threadIdx.x & 31;                      // 4-bf16 chunk
  if (g >= n) return;
  int e0 = rowptr[g], e1 = rowptr[g + 1];
  float4 a0 = make_float4(0.f,0.f,0.f,0.f);
  float4 a1 = make_float4(0.f,0.f,0.f,0.f);
  int e = e0;
  for (; e + 2 <= e1; e += 2){
    int s0 = eid[e], s1 = eid[e + 1];
    ushort4 u0 = *reinterpret_cast<const ushort4*>(&XB[(size_t)s0 * D + l * 4]);
    ushort4 u1 = *reinterpret_cast<const ushort4*>(&XB[(size_t)s1 * D + l * 4]);
    float4 f0 = bf4f(u0), f1 = bf4f(u1);
    a0.x += f0.x; a0.y += f0.y; a0.z += f0.z; a0.w += f0.w;
    a1.x += f1.x; a1.y += f1.y; a1.z += f1.z; a1.w += f1.w;
  }
  if (e < e1){
    int s0 = eid[e];
    ushort4 u0 = *reinterpret_cast<const ushort4*>(&XB[(size_t)s0 * D + l * 4]);
    float4 f0 = bf4f(u0);
    a0.x += f0.x; a0.y += f0.y; a0.z += f0.z; a0.w += f0.w;
  }
  float sc = 1.f / fmaxf((float)(e1 - e0), 1.f);
  float4 o;
  o.x = (a0.x + a1.x) * sc; o.y = (a0.y + a1.y) * sc;
  o.z = (a0.z + a1.z) * sc; o.w = (a0.w + a1.w) * sc;
  *reinterpret_cast<float4*>(&AG[(size_t)g * D + l * 4]) = o;
}

// ---------------- SAGE layer via split-bf16 MFMA ----------------
__global__ __launch_bounds__(256) void k_sage_mfma(const float* __restrict__ XS, const float* __restrict__ AG,
    const unsigned short* __restrict__ BTH, const unsigned short* __restrict__ BTL,
    const float* __restrict__ Bb, const float* __restrict__ GM, const float* __restrict__ BT,
    const float* __restrict__ RM, const float* __restrict__ RV,
    float* __restrict__ H, unsigned short* __restrict__ HB, int n, int donan)
{
  __shared__ unsigned short Ah[64 * 40];
  __shared__ unsigned short Al[64 * 40];
  __shared__ unsigned short Bh[128 * 40];
  __shared__ unsigned short Bl[128 * 40];

  int t  = threadIdx.x;
  int l  = t & 63;
  int wv = t >> 6;          // wave 0..3 -> rows wv*16..+15
  int lm = l & 15;          // frag row (A) / col (B,D)
  int lk = l >> 4;          // k-group 0..3
  int node0 = blockIdx.x * 64;

  f32x4 acc[8];
  #pragma unroll
  for (int f = 0; f < 8; ++f) acc[f] = (f32x4){0.f, 0.f, 0.f, 0.f};

  for (int step = 0; step < 8; ++step){
    int k0 = step * 32;                          // global k in [0,256)
    const float* srcA = (step < 4) ? XS : AG;
    int koff = (step < 4) ? k0 : (k0 - 128);

    __syncthreads();
    // ---- stage A: 64 rows x 32 k fp32 -> hi/lo bf16 ----
    #pragma unroll
    for (int i = 0; i < 2; ++i){
      int c   = t + i * 256;
      int row = c >> 3, c4 = c & 7;
      int node = min(node0 + row, n - 1);
      float4 v = *reinterpret_cast<const float4*>(&srcA[(size_t)node * D + koff + c4 * 4]);
      const float* vp = (const float*)&v;
      unsigned short hh[4], ll[4];
      #pragma unroll
      for (int j = 0; j < 4; ++j){
        unsigned short hi = f2bf_rn(vp[j]);
        hh[j] = hi;
        ll[j] = f2bf_rn(vp[j] - bf2f(hi));
      }
      uint2 wh, wl;
      wh.x = (unsigned)hh[0] | ((unsigned)hh[1] << 16);
      wh.y = (unsigned)hh[2] | ((unsigned)hh[3] << 16);
      wl.x = (unsigned)ll[0] | ((unsigned)ll[1] << 16);
      wl.y = (unsigned)ll[2] | ((unsigned)ll[3] << 16);
      *reinterpret_cast<uint2*>(&Ah[row * 40 + c4 * 4]) = wh;
      *reinterpret_cast<uint2*>(&Al[row * 40 + c4 * 4]) = wl;
    }
    // ---- stage B: 128 cols x 32 k bf16 hi+lo ----
    #pragma unroll
    for (int i = 0; i < 2; ++i){
      int c   = t + i * 256;
      int col = c >> 2, q = c & 3;
      *reinterpret_cast<uint4*>(&Bh[col * 40 + q * 8]) =
          *reinterpret_cast<const uint4*>(&BTH[col * 256 + k0 + q * 8]);
      *reinterpret_cast<uint4*>(&Bl[col * 40 + q * 8]) =
          *reinterpret_cast<const uint4*>(&BTL[col * 256 + k0 + q * 8]);
    }
    __syncthreads();

    // ---- MFMA: 8 col-frags x 3 split terms ----
    bf16x8 afh = *reinterpret_cast<const bf16x8*>(&Ah[(wv * 16 + lm) * 40 + lk * 8]);
    bf16x8 afl = *reinterpret_cast<const bf16x8*>(&Al[(wv * 16 + lm) * 40 + lk * 8]);
    #pragma unroll
    for (int f = 0; f < 8; ++f){
      bf16x8 bfh = *reinterpret_cast<const bf16x8*>(&Bh[(f * 16 + lm) * 40 + lk * 8]);
      bf16x8 bfl = *reinterpret_cast<const bf16x8*>(&Bl[(f * 16 + lm) * 40 + lk * 8]);
      acc[f] = __builtin_amdgcn_mfma_f32_16x16x32_bf16(afh, bfh, acc[f], 0, 0, 0);
      acc[f] = __builtin_amdgcn_mfma_f32_16x16x32_bf16(afl, bfh, acc[f], 0, 0, 0);
      acc[f] = __builtin_amdgcn_mfma_f32_16x16x32_bf16(afh, bfl, acc[f], 0, 0, 0);
    }
  }

  // ---- epilogue: BN + leaky relu (+ nan_to_num layer 2) ----
  #pragma unroll
  for (int f = 0; f < 8; ++f){
    int col = f * 16 + lm;
    float s  = GM[col] * rsqrtf(RV[col] + BN_EPS);
    float cj = (Bb[col] - RM[col]) * s + BT[col];
    #pragma unroll
    for (int r = 0; r < 4; ++r){
      int node = node0 + wv * 16 + lk * 4 + r;
      if (node < n){
        float v = lrelu(acc[f][r] * s + cj);
        if (donan && (v != v)) v = 1e-14f;
        H[(size_t)node * D + col] = v;
        if (HB) HB[(size_t)node * D + col] = f2bf_rn(v);
      }
    }
  }
}

// ---------------- candidate MLP via split-bf16 MFMA ----------------
__global__ __launch_bounds__(256) void k_mlp_mfma(const float* __restrict__ H,
    const int* __restrict__ cu, const int* __restrict__ cv, const float* __restrict__ cf,
    const unsigned short* __restrict__ W0H, const unsigned short* __restrict__ W0L,
    const float* __restrict__ mw0, const float* __restrict__ mb0,
    const unsigned short* __restrict__ W1H, const unsigned short* __restrict__ W1L,
    const float* __restrict__ mb1, const float* __restrict__ mw2, const float* __restrict__ mb2,
    float* __restrict__ y, int C)
{
  __shared__ unsigned short zh[4][32 * 72];   // per-wave z tile, hi (rows 144B)
  __shared__ unsigned short zl[4][32 * 72];   // per-wave z tile, lo

  int t = threadIdx.x;
  int wv = t >> 6, l = t & 63, lm = l & 15, lk = l >> 4;
  int candbase = blockIdx.x * 128 + wv * 32;

  int c0 = min(candbase + lm,      C - 1);
  int c1 = min(candbase + 16 + lm, C - 1);
  int nu0 = cu[c0], nv0 = cv[c0];
  int nu1 = cu[c1], nv1 = cv[c1];

  // ---- layer 1: K = 256 via MFMA ----
  f32x4 acc[2][4];
  #pragma unroll
  for (int m = 0; m < 2; ++m)
    #pragma unroll
    for (int f = 0; f < 4; ++f) acc[m][f] = (f32x4){0.f, 0.f, 0.f, 0.f};

  #pragma unroll
  for (int s = 0; s < 8; ++s){
    int n0 = (s < 4) ? nu0 : nv0;
    int n1 = (s < 4) ? nu1 : nv1;
    int koff = (s & 3) * 32 + lk * 8;
    const float4* p0 = reinterpret_cast<const float4*>(&H[(size_t)n0 * D + koff]);
    const float4* p1 = reinterpret_cast<const float4*>(&H[(size_t)n1 * D + koff]);
    float4 a00 = p0[0], a01 = p0[1];
    float4 a10 = p1[0], a11 = p1[1];
    uint4 h0, l0, h1, l1;
    split8(a00, a01, h0, l0);
    split8(a10, a11, h1, l1);
    bf16x8 afh0 = *reinterpret_cast<bf16x8*>(&h0);
    bf16x8 afl0 = *reinterpret_cast<bf16x8*>(&l0);
    bf16x8 afh1 = *reinterpret_cast<bf16x8*>(&h1);
    bf16x8 afl1 = *reinterpret_cast<bf16x8*>(&l1);

    int k0 = s * 32 + lk * 8;
    #pragma unroll
    for (int f = 0; f < 4; ++f){
      int col = f * 16 + lm;
      bf16x8 bh = *reinterpret_cast<const bf16x8*>(&W0H[(size_t)col * 264 + k0]);
      bf16x8 bl = *reinterpret_cast<const bf16x8*>(&W0L[(size_t)col * 264 + k0]);
      acc[0][f] = __builtin_amdgcn_mfma_f32_16x16x32_bf16(afh0, bh, acc[0][f], 0, 0, 0);
      acc[0][f] = __builtin_amdgcn_mfma_f32_16x16x32_bf16(afl0, bh, acc[0][f], 0, 0, 0);
      acc[0][f] = __builtin_amdgcn_mfma_f32_16x16x32_bf16(afh0, bl, acc[0][f], 0, 0, 0);
      acc[1][f] = __builtin_amdgcn_mfma_f32_16x16x32_bf16(afh1, bh, acc[1][f], 0, 0, 0);
      acc[1][f] = __builtin_amdgcn_mfma_f32_16x16x32_bf16(afl1, bh, acc[1][f], 0, 0, 0);
      acc[1][f] = __builtin_amdgcn_mfma_f32_16x16x32_bf16(afh1, bl, acc[1][f], 0, 0, 0);
    }
  }

  // ---- L1 epilogue: bias + feat term + lrelu, write z hi/lo to LDS ----
  float cfv[2][4];
  #pragma unroll
  for (int m = 0; m < 2; ++m)
    #pragma unroll
    for (int r = 0; r < 4; ++r)
      cfv[m][r] = cf[min(candbase + m * 16 + lk * 4 + r, C - 1)];

  #pragma unroll
  for (int f = 0; f < 4; ++f){
    int col = f * 16 + lm;
    float b0v = mb0[col];
    float wfv = mw0[256 * 64 + col];
    #pragma unroll
    for (int m = 0; m < 2; ++m){
      #pragma unroll
      for (int r = 0; r < 4; ++r){
        int cl = m * 16 + lk * 4 + r;
        float z = lrelu(acc[m][f][r] + b0v + cfv[m][r] * wfv);
        unsigned short h16 = f2bf_rn(z);
        zh[wv][cl * 72 + col] = h16;
        zl[wv][cl * 72 + col] = f2bf_rn(z - bf2f(h16));
      }
    }
  }
  // wave-local LDS: hardware lgkmcnt ordering covers write->read, no barrier

  // ---- layer 2: K = 64 via MFMA ----
  f32x4 a2[2][4];
  #pragma unroll
  for (int m = 0; m < 2; ++m)
    #pragma unroll
    for (int f = 0; f < 4; ++f) a2[m][f] = (f32x4){0.f, 0.f, 0.f, 0.f};

  #pragma unroll
  for (int s2 = 0; s2 < 2; ++s2){
    int kk = s2 * 32 + lk * 8;
    bf16x8 azh0 = *reinterpret_cast<const bf16x8*>(&zh[wv][(0 * 16 + lm) * 72 + kk]);
    bf16x8 azl0 = *reinterpret_cast<const bf16x8*>(&zl[wv][(0 * 16 + lm) * 72 + kk]);
    bf16x8 azh1 = *reinterpret_cast<const bf16x8*>(&zh[wv][(1 * 16 + lm) * 72 + kk]);
    bf16x8 azl1 = *reinterpret_cast<const bf16x8*>(&zl[wv][(1 * 16 + lm) * 72 + kk]);
    #pragma unroll
    for (int f = 0; f < 4; ++f){
      int col = f * 16 + lm;
      bf16x8 bh = *reinterpret_cast<const bf16x8*>(&W1H[(size_t)col * 64 + kk]);
      bf16x8 bl = *reinterpret_cast<const bf16x8*>(&W1L[(size_t)col * 64 + kk]);
      a2[0][f] = __builtin_amdgcn_mfma_f32_16x16x32_bf16(azh0, bh, a2[0][f], 0, 0, 0);
      a2[0][f] = __builtin_amdgcn_mfma_f32_16x16x32_bf16(azl0, bh, a2[0][f], 0, 0, 0);
      a2[0][f] = __builtin_amdgcn_mfma_f32_16x16x32_bf16(azh0, bl, a2[0][f], 0, 0, 0);
      a2[1][f] = __builtin_amdgcn_mfma_f32_16x16x32_bf16(azh1, bh, a2[1][f], 0, 0, 0);
      a2[1][f] = __builtin_amdgcn_mfma_f32_16x16x32_bf16(azl1, bh, a2[1][f], 0, 0, 0);
      a2[1][f] = __builtin_amdgcn_mfma_f32_16x16x32_bf16(azh1, bl, a2[1][f], 0, 0, 0);
    }
  }

  // ---- layer 3: 64 -> 1 : per-lane partial + 16-lane xor reduce ----
  float p00 = 0.f, p01 = 0.f, p02 = 0.f, p03 = 0.f;
  float p10 = 0.f, p11 = 0.f, p12 = 0.f, p13 = 0.f;
  #pragma unroll
  for (int f = 0; f < 4; ++f){
    int col = f * 16 + lm;
    float b1v = mb1[col];
    float w2v = mw2[col];
    p00 = fmaf(lrelu(a2[0][f][0] + b1v), w2v, p00);
    p01 = fmaf(lrelu(a2[0][f][1] + b1v), w2v, p01);
    p02 = fmaf(lrelu(a2[0][f][2] + b1v), w2v, p02);
    p03 = fmaf(lrelu(a2[0][f][3] + b1v), w2v, p03);
    p10 = fmaf(lrelu(a2[1][f][0] + b1v), w2v, p10);
    p11 = fmaf(lrelu(a2[1][f][1] + b1v), w2v, p11);
    p12 = fmaf(lrelu(a2[1][f][2] + b1v), w2v, p12);
    p13 = fmaf(lrelu(a2[1][f][3] + b1v), w2v, p13);
  }
  #pragma unroll
  for (int off = 1; off < 16; off <<= 1){
    p00 += __shfl_xor(p00, off); p01 += __shfl_xor(p01, off);
    p02 += __shfl_xor(p02, off); p03 += __shfl_xor(p03, off);
    p10 += __shfl_xor(p10, off); p11 += __shfl_xor(p11, off);
    p12 += __shfl_xor(p12, off); p13 += __shfl_xor(p13, off);
  }
  if (lm == 0){
    float b2 = mb2[0];
    int base0 = candbase + lk * 4;
    int base1 = candbase + 16 + lk * 4;
    if (base0 + 0 < C) y[base0 + 0] = p00 + b2;
    if (base0 + 1 < C) y[base0 + 1] = p01 + b2;
    if (base0 + 2 < C) y[base0 + 2] = p02 + b2;
    if (base0 + 3 < C) y[base0 + 3] = p03 + b2;
    if (base1 + 0 < C) y[base1 + 0] = p10 + b2;
    if (base1 + 1 < C) y[base1 + 1] = p11 + b2;
    if (base1 + 2 < C) y[base1 + 2] = p12 + b2;
    if (base1 + 3 < C) y[base1 + 3] = p13 + b2;
  }
}

// ---------------- softmax over C logits ----------------
__global__ __launch_bounds__(256) void k_red1(const float* __restrict__ y,
                                              float* __restrict__ bmax, float* __restrict__ bsum, int C){
  __shared__ float sm[4];
  __shared__ float ss[4];
  int t = threadIdx.x;
  float m = -3.4e38f;
  for (int i = blockIdx.x * 256 + t; i < C; i += gridDim.x * 256) m = fmaxf(m, y[i]);
  for (int o = 32; o; o >>= 1) m = fmaxf(m, __shfl_xor(m, o));
  if ((t & 63) == 0) sm[t >> 6] = m;
  __syncthreads();
  float bm = fmaxf(fmaxf(sm[0], sm[1]), fmaxf(sm[2], sm[3]));
  float s = 0.f;
  for (int i = blockIdx.x * 256 + t; i < C; i += gridDim.x * 256) s += expf(y[i] - bm);
  for (int o = 32; o; o >>= 1) s += __shfl_xor(s, o);
  if ((t & 63) == 0) ss[t >> 6] = s;
  __syncthreads();
  if (t == 0){ bmax[blockIdx.x] = bm; bsum[blockIdx.x] = ss[0] + ss[1] + ss[2] + ss[3]; }
}

__global__ __launch_bounds__(256) void k_red2(const float* __restrict__ bmax, const float* __restrict__ bsum,
                                              float* __restrict__ g, int nb){
  __shared__ float sm[4];
  __shared__ float ss[4];
  int t = threadIdx.x;
  float m0 = (t < nb) ? bmax[t] : -3.4e38f;
  float m = m0;
  for (int o = 32; o; o >>= 1) m = fmaxf(m, __shfl_xor(m, o));
  if ((t & 63) == 0) sm[t >> 6] = m;
  __syncthreads();
  float gm = fmaxf(fmaxf(sm[0], sm[1]), fmaxf(sm[2], sm[3]));
  float s = (t < nb) ? bsum[t] * expf(m0 - gm) : 0.f;
  for (int o = 32; o; o >>= 1) s += __shfl_xor(s, o);
  if ((t & 63) == 0) ss[t >> 6] = s;
  __syncthreads();
  if (t == 0){ g[0] = gm; g[1] = 1.f / (ss[0] + ss[1] + ss[2] + ss[3]); }
}

__global__ __launch_bounds__(256) void k_red3(const float* __restrict__ y, const float* __restrict__ g,
                                              float* __restrict__ out, int C){
  int i = blockIdx.x * 256 + threadIdx.x;
  if (i < C) out[i] = expf(y[i] - g[0]) * g[1];
}

extern "C" void kernel_launch(void* const* d_in, const int* in_sizes, int n_in,
                              void* d_out, int out_size, void* d_ws, size_t ws_size,
                              hipStream_t stream)
{
  const float* x   = (const float*)d_in[0];
  const int*   src = (const int*)  d_in[1];
  const int*   dst = (const int*)  d_in[2];
  const int*   cu  = (const int*)  d_in[3];
  const int*   cv  = (const int*)  d_in[4];
  const float* cf  = (const float*)d_in[5];
  const float* ws0 = (const float*)d_in[6];
  const float* wn0 = (const float*)d_in[7];
  const float* b0  = (const float*)d_in[8];
  const float* g0  = (const float*)d_in[9];
  const float* be0 = (const float*)d_in[10];
  const float* rm0 = (const float*)d_in[11];
  const float* rv0 = (const float*)d_in[12];
  const float* ws1 = (const float*)d_in[13];
  const float* wn1 = (const float*)d_in[14];
  const float* b1  = (const float*)d_in[15];
  const float* g1  = (const float*)d_in[16];
  const float* be1 = (const float*)d_in[17];
  const float* rm1 = (const float*)d_in[18];
  const float* rv1 = (const float*)d_in[19];
  const float* mw0 = (const float*)d_in[20];
  const float* mb0 = (const float*)d_in[21];
  const float* mw1 = (const float*)d_in[22];
  const float* mb1 = (const float*)d_in[23];
  const float* mw2 = (const float*)d_in[24];
  const float* mb2 = (const float*)d_in[25];

  float* out = (float*)d_out;   // [C] y then [C] softmax

  char* w = (char*)d_ws;
  float* aggn  = (float*)w; w += (size_t)N_NODES * D * 4;
  float* h0    = (float*)w; w += (size_t)N_NODES * D * 4;
  float* h1    = (float*)w; w += (size_t)N_NODES * D * 4;
  int* cnt     = (int*)w;   w += (size_t)N_NODES * 4;          // -> SAGE weights L0
  int* rowptr  = (int*)w;   w += (size_t)(N_NODES + 1) * 4;
  int* cur     = (int*)w;   w += (size_t)N_NODES * 4;          // -> SAGE weights L1
  int* eid     = (int*)w;   w += (size_t)N_EDGES * 4;          // holds eid16 (ushort)
  int* gcnt    = (int*)w;   w += (size_t)(NB2 + 8) * 4;
  int* bbase   = (int*)w;   w += (size_t)(NB2 + 1) * 4;
  float* bmax  = (float*)w; w += 256 * 4;
  float* bsumF = (float*)w; w += 256 * 4;
  float* gred  = (float*)w; w += 2 * 4;
  // split MLP weights (transposed): w0 [64][264] hi/lo, w1 [64][64] hi/lo
  unsigned short* w0th = (unsigned short*)w; w += (size_t)64 * 264 * 2;
  unsigned short* w0tl = (unsigned short*)w; w += (size_t)64 * 264 * 2;
  unsigned short* w1th = (unsigned short*)w; w += (size_t)64 * 64 * 2;
  unsigned short* w1tl = (unsigned short*)w; w += (size_t)64 * 64 * 2;

  unsigned short* eid16 = (unsigned short*)eid;

  // edge bins OVERLAY h0 (h0 only live sage0 -> sage1, after CSR build):
  unsigned* ebin = (unsigned*)h0;      // NB2*BCAP*4 = 3.7 MB << 25.6 MB

  // bf16 gather planes OVERLAY the h1 region:
  //   xb  live [cvt_x .. agg0],  hb0 live [sage0 .. agg1],  h1 live [sage1 .. mlp]
  unsigned short* xb  = (unsigned short*)h1;
  unsigned short* hb0 = xb + (size_t)N_NODES * D;

  // split-bf16 SAGE weight buffers alias the cnt/cur scratch:
  unsigned short* bth0 = (unsigned short*)cnt;
  unsigned short* btl0 = bth0 + 128 * 256;
  unsigned short* bth1 = (unsigned short*)cur;
  unsigned short* btl1 = bth1 + 128 * 256;

  // ---- CSR build (tiled LDS binning; writes coalesced by construction) ----
  hipMemsetAsync(gcnt, 0, (size_t)NB2 * 4, stream);
  k_bin   <<<NTILE, 256, 0, stream>>>(src, dst, gcnt, ebin, N_EDGES);
  k_bscan2<<<1, 256, 0, stream>>>(gcnt, bbase, rowptr);
  k_bfin  <<<NB2, 256, 0, stream>>>(gcnt, bbase, ebin, eid16, rowptr, N_NODES);

  // ---- weight conversions (independent) ----
  k_cvt_w<<<128, 256, 0, stream>>>(ws0, wn0, bth0, btl0);
  k_cvt_w<<<128, 256, 0, stream>>>(ws1, wn1, bth1, btl1);
  k_cvt_mlp<<<64, 256, 0, stream>>>(mw0, 257, 264, w0th, w0tl);
  k_cvt_mlp<<<64, 256, 0, stream>>>(mw1, 64, 64, w1th, w1tl);
  k_cvt_x<<<(N_NODES * D / 4 + 255) / 256, 256, 0, stream>>>(x, xb, N_NODES * D / 4);

  int GB = (N_NODES + 63) / 64;     // 782
  k_agg_bf<<<(N_NODES + 7) / 8, 256, 0, stream>>>(xb, rowptr, eid16, aggn, N_NODES);
  k_sage_mfma<<<GB, 256, 0, stream>>>(x,  aggn, bth0, btl0, b0, g0, be0, rm0, rv0, h0, hb0, N_NODES, 0);
  k_agg_bf<<<(N_NODES + 7) / 8, 256, 0, stream>>>(hb0, rowptr, eid16, aggn, N_NODES);
  k_sage_mfma<<<GB, 256, 0, stream>>>(h0, aggn, bth1, btl1, b1, g1, be1, rm1, rv1, h1, (unsigned short*)0, N_NODES, 1);

  k_mlp_mfma<<<(N_CAND + 127) / 128, 256, 0, stream>>>(h1, cu, cv, cf,
      w0th, w0tl, mw0, mb0, w1th, w1tl, mb1, mw2, mb2, out, N_CAND);

  k_red1<<<256, 256, 0, stream>>>(out, bmax, bsumF, N_CAND);
  k_red2<<<1, 256, 0, stream>>>(bmax, bsumF, gred, 256);
  k_red3<<<(N_CAND + 255) / 256, 256, 0, stream>>>(out, gred, out + N_CAND, N_CAND);
}